// Round 1
// baseline (1016.808 us; speedup 1.0000x reference)
//
#include <hip/hip_runtime.h>
#include <hip/hip_cooperative_groups.h>

namespace cg = cooperative_groups;

typedef unsigned short u16;
typedef unsigned int u32;
typedef unsigned long long u64;
typedef __attribute__((ext_vector_type(8))) short short8;
typedef __attribute__((ext_vector_type(4))) float f32x4;

#define ICAPS 512
#define IDIM 128
#define NFLAT 512  // NCAPS(16) * ODIM(32)

__device__ __forceinline__ float b2f(u16 h) {
    union { u32 u; float f; } x; x.u = ((u32)h) << 16; return x.f;
}
__device__ __forceinline__ u16 f2b(float f) {
    union { float f; u32 u; } x; x.f = f;
    return (u16)((x.u + 0x7FFFu + ((x.u >> 16) & 1u)) >> 16);
}

// ---------------------------------------------------------------------------
// GEMM: unchanged from the 245 µs version (memory-bound, W read exactly once).
// ---------------------------------------------------------------------------
__global__ __launch_bounds__(256, 4) void gemm_kernel(const float* __restrict__ x,
                                                      const float* __restrict__ W,
                                                      u16* __restrict__ uhat) {
    __shared__ __align__(16) u16 As[64 * 136];   // x[b][k] bf16, pitch 136
    const int i = blockIdx.x >> 2;
    const int chunk = blockIdx.x & 3;
    const int t = threadIdx.x;

    // Stage A: 64 rows x 128 k of x for this i; 2048 float4, 8/thread
    {
        const float4* xa = (const float4*)x;
        float4 av[8];
        #pragma unroll
        for (int l = 0; l < 8; ++l) {
            int id = l * 256 + t;
            av[l] = xa[(size_t)((id >> 5) * ICAPS + i) * 32 + (id & 31)];
        }
        #pragma unroll
        for (int l = 0; l < 8; ++l) {
            int id = l * 256 + t;
            int row = id >> 5, kq = id & 31;
            union { u16 h[4]; u64 q; } pk;
            pk.h[0] = f2b(av[l].x); pk.h[1] = f2b(av[l].y);
            pk.h[2] = f2b(av[l].z); pk.h[3] = f2b(av[l].w);
            *(u64*)&As[row * 136 + kq * 4] = pk.q;
        }
    }
    __syncthreads();

    const int lane = t & 63;
    const int w = t >> 6;
    const int ln = lane & 15;
    const int q = lane >> 4;

    const float* colbase[2];
    #pragma unroll
    for (int nt = 0; nt < 2; ++nt) {
        int c = (2 * w + nt) * 16 + ln;
        int jj = c >> 5, d = c & 31;
        colbase[nt] = W + (size_t)(i * 16 + chunk * 4 + jj) * 128 * 32 + d;
    }

    f32x4 acc[4][2] = {};
    #pragma unroll
    for (int ks = 0; ks < 4; ++ks) {
        const int ko = ks * 32 + q * 8;
        short8 a[4], bb[2];
        #pragma unroll
        for (int mt = 0; mt < 4; ++mt)
            a[mt] = *(const short8*)&As[(mt * 16 + ln) * 136 + ko];
        #pragma unroll
        for (int nt = 0; nt < 2; ++nt) {
            const float* p = colbase[nt] + (size_t)ko * 32;
            float wv[8];
            #pragma unroll
            for (int e = 0; e < 8; ++e) wv[e] = p[e * 32];   // offset e*128B imm
            #pragma unroll
            for (int e = 0; e < 8; ++e) bb[nt][e] = (short)f2b(wv[e]);
        }
        #pragma unroll
        for (int mt = 0; mt < 4; ++mt)
            #pragma unroll
            for (int nt = 0; nt < 2; ++nt)
                acc[mt][nt] = __builtin_amdgcn_mfma_f32_16x16x32_bf16(a[mt], bb[nt], acc[mt][nt], 0, 0, 0);
    }
    // C/D: col = lane&15, row = q*4 + reg (m89/m91-verified)
    #pragma unroll
    for (int mt = 0; mt < 4; ++mt)
        #pragma unroll
        for (int nt = 0; nt < 2; ++nt) {
            int n = chunk * 128 + (2 * w + nt) * 16 + ln;
            #pragma unroll
            for (int r = 0; r < 4; ++r) {
                int brow = mt * 16 + q * 4 + r;
                uhat[((size_t)brow * ICAPS + i) * NFLAT + n] = f2b(acc[mt][nt][r]);
            }
        }
}

// ---------------------------------------------------------------------------
// Fused routing: p0 + combine + route + combine + route + fin in ONE
// cooperative kernel. Grid 1024 = (b=64) x (ch=16), 256 threads.
// LDS 14.3 KB, VGPR capped at 128 => 4 blocks/CU co-resident (exactly grid).
// s0 persists in LDS across grid syncs (block stays resident).
// Only ~2 MB of q-partials is dirty at each sync (vs full-kernel boundary).
// ---------------------------------------------------------------------------
__device__ __forceinline__ void route_accum(const u16* __restrict__ uhat,
                                            float* __restrict__ qout,
                                            const float* __restrict__ osum,
                                            float (*__restrict__ red)[NFLAT],
                                            int b, int ch, int t) {
    const int wv = t >> 6, l = t & 63;
    float os[8], acc[8];
    #pragma unroll
    for (int e = 0; e < 8; ++e) { os[e] = osum[l * 8 + e]; acc[e] = 0.f; }
    for (int ii = 0; ii < 8; ++ii) {
        int i = ch * 32 + wv * 8 + ii;
        union { uint4 v; u16 h[8]; } tmp;
        tmp.v = *(const uint4*)&uhat[((size_t)b * ICAPS + i) * NFLAT + l * 8];
        float u[8];
        #pragma unroll
        for (int e = 0; e < 8; ++e) u[e] = b2f(tmp.h[e]);
        float d = 0.f;
        #pragma unroll
        for (int e = 0; e < 8; ++e) d += u[e] * os[e];
        d += __shfl_xor(d, 1); d += __shfl_xor(d, 2);   // quad = one j
        float mx = d;
        mx = fmaxf(mx, __shfl_xor(mx, 4));  mx = fmaxf(mx, __shfl_xor(mx, 8));
        mx = fmaxf(mx, __shfl_xor(mx, 16)); mx = fmaxf(mx, __shfl_xor(mx, 32));
        float ex = __expf(d - mx);
        float ss = ex;
        ss += __shfl_xor(ss, 4);  ss += __shfl_xor(ss, 8);
        ss += __shfl_xor(ss, 16); ss += __shfl_xor(ss, 32);
        float c = ex / ss;
        #pragma unroll
        for (int e = 0; e < 8; ++e) acc[e] += c * u[e];
    }
    #pragma unroll
    for (int e = 0; e < 8; ++e) red[wv][l * 8 + e] = acc[e];
    __syncthreads();
    const int bx = b * 16 + ch;
    qout[(size_t)bx * NFLAT + t] =
        red[0][t] + red[1][t] + red[2][t] + red[3][t];
    qout[(size_t)bx * NFLAT + 256 + t] =
        red[0][t + 256] + red[1][t + 256] + red[2][t + 256] + red[3][t + 256];
}

__global__ __launch_bounds__(256, 4) void route_fused(const u16* __restrict__ uhat,
                                                      float* __restrict__ q0,
                                                      float* __restrict__ q1,
                                                      float* __restrict__ q2,
                                                      float* __restrict__ out) {
    __shared__ __align__(16) float red[4][NFLAT];
    __shared__ float osum[NFLAT];
    __shared__ float s0sav[NFLAT];
    __shared__ float s1sav[NFLAT];
    const int b = blockIdx.x >> 4;
    const int ch = blockIdx.x & 15;
    const int t = threadIdx.x;
    const int wv = t >> 6, l = t & 63;
    cg::grid_group grid = cg::this_grid();

    // ---- phase 0 (= p0): q0[bx] = sum_{i in slice} uhat ----
    {
        float acc[8] = {0.f, 0.f, 0.f, 0.f, 0.f, 0.f, 0.f, 0.f};
        for (int ii = 0; ii < 8; ++ii) {
            int i = ch * 32 + wv * 8 + ii;
            union { uint4 v; u16 h[8]; } tmp;
            tmp.v = *(const uint4*)&uhat[((size_t)b * ICAPS + i) * NFLAT + l * 8];
            #pragma unroll
            for (int e = 0; e < 8; ++e) acc[e] += b2f(tmp.h[e]);
        }
        #pragma unroll
        for (int e = 0; e < 8; ++e) red[wv][l * 8 + e] = acc[e];
        __syncthreads();
        q0[(size_t)blockIdx.x * NFLAT + t] =
            red[0][t] + red[1][t] + red[2][t] + red[3][t];
        q0[(size_t)blockIdx.x * NFLAT + 256 + t] =
            red[0][t + 256] + red[1][t + 256] + red[2][t + 256] + red[3][t + 256];
    }
    __threadfence();   // release q0 (agent scope -> L2 writeback)
    grid.sync();
    __threadfence();   // acquire (invalidate stale lines, cross-XCD)

    // ---- phase 1: s0 = sum_ch q0 (kept in LDS); osum = squash(s0/16); route -> q1
    {
        #pragma unroll
        for (int rep = 0; rep < 2; ++rep) {
            int n = rep * 256 + t;
            float a = 0.f;
            #pragma unroll
            for (int c2 = 0; c2 < 16; ++c2)
                a += q0[(size_t)(b * 16 + c2) * NFLAT + n];
            s0sav[n] = a;
        }
        __syncthreads();
        const int j = t >> 4, g = t & 15;
        const int n0 = j * 32 + 2 * g;
        float v0 = s0sav[n0] * 0.0625f, v1 = s0sav[n0 + 1] * 0.0625f;
        float p = v0 * v0 + v1 * v1;
        p += __shfl_xor(p, 1); p += __shfl_xor(p, 2);
        p += __shfl_xor(p, 4); p += __shfl_xor(p, 8);
        float sc = (p / (1.f + p)) / sqrtf(p + 1e-7f);
        osum[n0] = sc * v0; osum[n0 + 1] = sc * v1;
        __syncthreads();
        route_accum(uhat, q1, osum, red, b, ch, t);
    }
    __threadfence();
    grid.sync();
    __threadfence();

    // ---- phase 2: s1 = sum_ch q1; osum = squash(s0/16)+squash(s1); route -> q2
    {
        #pragma unroll
        for (int rep = 0; rep < 2; ++rep) {
            int n = rep * 256 + t;
            float a = 0.f;
            #pragma unroll
            for (int c2 = 0; c2 < 16; ++c2)
                a += q1[(size_t)(b * 16 + c2) * NFLAT + n];
            s1sav[n] = a;
        }
        __syncthreads();
        const int j = t >> 4, g = t & 15;
        const int n0 = j * 32 + 2 * g;
        float v0 = s0sav[n0] * 0.0625f, v1 = s0sav[n0 + 1] * 0.0625f;
        float p = v0 * v0 + v1 * v1;
        p += __shfl_xor(p, 1); p += __shfl_xor(p, 2);
        p += __shfl_xor(p, 4); p += __shfl_xor(p, 8);
        float sc = (p / (1.f + p)) / sqrtf(p + 1e-7f);
        float w0 = s1sav[n0], w1 = s1sav[n0 + 1];
        float pq = w0 * w0 + w1 * w1;
        pq += __shfl_xor(pq, 1); pq += __shfl_xor(pq, 2);
        pq += __shfl_xor(pq, 4); pq += __shfl_xor(pq, 8);
        float sc1 = (pq / (1.f + pq)) / sqrtf(pq + 1e-7f);
        osum[n0] = sc * v0 + sc1 * w0;
        osum[n0 + 1] = sc * v1 + sc1 * w1;
        __syncthreads();
        route_accum(uhat, q2, osum, red, b, ch, t);
    }
    __threadfence();
    grid.sync();
    __threadfence();

    // ---- phase 3 (= fin): 64 blocks (ch==0) compute out = squash(sum_ch q2)
    if (ch == 0) {
        const int j = t >> 4, g = t & 15;
        const int n0 = j * 32 + 2 * g;
        float v0 = 0.f, v1 = 0.f;
        #pragma unroll
        for (int c2 = 0; c2 < 16; ++c2) {
            v0 += q2[(size_t)(b * 16 + c2) * NFLAT + n0];
            v1 += q2[(size_t)(b * 16 + c2) * NFLAT + n0 + 1];
        }
        float p = v0 * v0 + v1 * v1;
        p += __shfl_xor(p, 1); p += __shfl_xor(p, 2);
        p += __shfl_xor(p, 4); p += __shfl_xor(p, 8);
        float sc = (p / (1.f + p)) / sqrtf(p + 1e-7f);
        out[b * NFLAT + n0]     = sc * v0;
        out[b * NFLAT + n0 + 1] = sc * v1;
    }
}

extern "C" void kernel_launch(void* const* d_in, const int* in_sizes, int n_in,
                              void* d_out, int out_size, void* d_ws, size_t ws_size,
                              hipStream_t stream) {
    // fp32 inputs (established R4). Resolve by element count.
    const float* x = nullptr;
    const float* W = nullptr;
    for (int a = 0; a < n_in; ++a) {
        if (in_sizes[a] == 64 * 512 * 128) x = (const float*)d_in[a];
        else if (in_sizes[a] == 512 * 16 * 128 * 32) W = (const float*)d_in[a];
    }
    if (!x) x = (const float*)d_in[0];
    if (!W) W = (const float*)d_in[1];

    char* ws = (char*)d_ws;
    const size_t U = 2ull * 64 * 512 * 512;          // uhat bytes = 33.5 MB
    u16*   uhat = (u16*)ws;
    float* q0 = (float*)(ws + U);                    // 1024*512 f32 = 2 MB
    float* q1 = (float*)(ws + U + (2ull << 20));
    float* q2 = (float*)(ws + U + (4ull << 20));
    float* out = (float*)d_out;

    hipLaunchKernelGGL(gemm_kernel, dim3(2048), dim3(256), 0, stream, x, W, uhat);

    void* args[5];
    args[0] = (void*)&uhat;
    args[1] = (void*)&q0;
    args[2] = (void*)&q1;
    args[3] = (void*)&q2;
    args[4] = (void*)&out;
    hipLaunchCooperativeKernel((const void*)route_fused, dim3(1024), dim3(256),
                               args, 0, stream);
}

// Round 2
// 253.560 us; speedup vs baseline: 4.0101x; 4.0101x over previous
//
#include <hip/hip_runtime.h>

typedef unsigned short u16;
typedef unsigned int u32;
typedef unsigned long long u64;
typedef __attribute__((ext_vector_type(8))) short short8;
typedef __attribute__((ext_vector_type(4))) float f32x4;

#define ICAPS 512
#define IDIM 128
#define NFLAT 512  // NCAPS(16) * ODIM(32)

__device__ __forceinline__ float b2f(u16 h) {
    union { u32 u; float f; } x; x.u = ((u32)h) << 16; return x.f;
}
__device__ __forceinline__ u16 f2b(float f) {
    union { float f; u32 u; } x; x.f = f;
    return (u16)((x.u + 0x7FFFu + ((x.u >> 16) & 1u)) >> 16);
}

// ---------------------------------------------------------------------------
// GEMM: u_hat[b,i,n] = sum_k x[b,i,k]*W[i,j(n),k,d(n)], n=j*32+d. fp32 inputs.
// Same interior as the 245 µs version (memory-bound, W read exactly once).
// NEW: epilogue repacks C through LDS (reusing As) so the uhat store is
// 4x dwordx4 coalesced per thread instead of 32x 2B scatter stores.
// ---------------------------------------------------------------------------
__global__ __launch_bounds__(256, 4) void gemm_kernel(const float* __restrict__ x,
                                                      const float* __restrict__ W,
                                                      u16* __restrict__ uhat) {
    __shared__ __align__(16) u16 As[64 * 136];   // x[b][k] bf16, pitch 136
    const int i = blockIdx.x >> 2;
    const int chunk = blockIdx.x & 3;
    const int t = threadIdx.x;

    // Stage A: 64 rows x 128 k of x for this i; 2048 float4, 8/thread
    {
        const float4* xa = (const float4*)x;
        float4 av[8];
        #pragma unroll
        for (int l = 0; l < 8; ++l) {
            int id = l * 256 + t;
            av[l] = xa[(size_t)((id >> 5) * ICAPS + i) * 32 + (id & 31)];
        }
        #pragma unroll
        for (int l = 0; l < 8; ++l) {
            int id = l * 256 + t;
            int row = id >> 5, kq = id & 31;
            union { u16 h[4]; u64 q; } pk;
            pk.h[0] = f2b(av[l].x); pk.h[1] = f2b(av[l].y);
            pk.h[2] = f2b(av[l].z); pk.h[3] = f2b(av[l].w);
            *(u64*)&As[row * 136 + kq * 4] = pk.q;
        }
    }
    __syncthreads();

    const int lane = t & 63;
    const int w = t >> 6;
    const int ln = lane & 15;
    const int q = lane >> 4;

    const float* colbase[2];
    #pragma unroll
    for (int nt = 0; nt < 2; ++nt) {
        int c = (2 * w + nt) * 16 + ln;
        int jj = c >> 5, d = c & 31;
        colbase[nt] = W + (size_t)(i * 16 + chunk * 4 + jj) * 128 * 32 + d;
    }

    f32x4 acc[4][2] = {};
    #pragma unroll
    for (int ks = 0; ks < 4; ++ks) {
        const int ko = ks * 32 + q * 8;
        short8 a[4], bb[2];
        #pragma unroll
        for (int mt = 0; mt < 4; ++mt)
            a[mt] = *(const short8*)&As[(mt * 16 + ln) * 136 + ko];
        #pragma unroll
        for (int nt = 0; nt < 2; ++nt) {
            const float* p = colbase[nt] + (size_t)ko * 32;
            float wv[8];
            #pragma unroll
            for (int e = 0; e < 8; ++e) wv[e] = p[e * 32];   // offset e*128B imm
            #pragma unroll
            for (int e = 0; e < 8; ++e) bb[nt][e] = (short)f2b(wv[e]);
        }
        #pragma unroll
        for (int mt = 0; mt < 4; ++mt)
            #pragma unroll
            for (int nt = 0; nt < 2; ++nt)
                acc[mt][nt] = __builtin_amdgcn_mfma_f32_16x16x32_bf16(a[mt], bb[nt], acc[mt][nt], 0, 0, 0);
    }

    // Epilogue: repack C via LDS (As is dead now; 64x136 u16 = exactly enough)
    __syncthreads();   // all waves done reading As
    #pragma unroll
    for (int mt = 0; mt < 4; ++mt)
        #pragma unroll
        for (int nt = 0; nt < 2; ++nt) {
            int nl = (2 * w + nt) * 16 + ln;
            #pragma unroll
            for (int r = 0; r < 4; ++r) {
                int brow = mt * 16 + q * 4 + r;
                As[brow * 136 + nl] = f2b(acc[mt][nt][r]);
            }
        }
    __syncthreads();
    // 4 passes: 16 rows/pass, 16 lanes/row x 8 u16 (16B) -> 256B/row coalesced
    #pragma unroll
    for (int p = 0; p < 4; ++p) {
        int brow = p * 16 + (t >> 4);
        int col8 = (t & 15) * 8;
        uint4 v = *(const uint4*)&As[brow * 136 + col8];
        *(uint4*)&uhat[((size_t)brow * ICAPS + i) * NFLAT + chunk * 128 + col8] = v;
    }
}

// ---------------------------------------------------------------------------
// route_all: the ENTIRE routing (3 iterations + final squash) in one kernel.
// Routing is independent per batch element b -> one block per b, NO grid
// sync needed (this is what the failed cooperative version missed).
// Grid 64 x 1024 threads (16 waves). Each iteration streams this b's
// uhat slice (512 KB, L3-resident) once; s-reduction over 16 waves in LDS.
// LDS: red 32KB + sbuf 2KB + osum 2KB = 36KB.
// ---------------------------------------------------------------------------
__global__ __launch_bounds__(1024, 1) void route_all(const u16* __restrict__ uhat,
                                                     float* __restrict__ out) {
    __shared__ __align__(16) float red[16][NFLAT];
    __shared__ float sbuf[NFLAT];
    __shared__ float osum[NFLAT];
    const int b = blockIdx.x;
    const int t = threadIdx.x;
    const int wv = t >> 6, l = t & 63;
    // wave wv owns i = wv*32 .. wv*32+31; lane l owns n = l*8 .. l*8+7
    const u16* ubase = uhat + ((size_t)b * ICAPS + (size_t)wv * 32) * NFLAT + l * 8;

    float acc[8];

    // ---- iter 0: c = 1/16 uniform -> s0 = (sum_i uhat)/16 ----
    #pragma unroll
    for (int e = 0; e < 8; ++e) acc[e] = 0.f;
    #pragma unroll 4
    for (int ii = 0; ii < 32; ++ii) {
        union { uint4 v; u16 h[8]; } tmp;
        tmp.v = *(const uint4*)&ubase[(size_t)ii * NFLAT];
        #pragma unroll
        for (int e = 0; e < 8; ++e) acc[e] += b2f(tmp.h[e]);
    }
    #pragma unroll
    for (int e = 0; e < 8; ++e) red[wv][l * 8 + e] = acc[e];
    __syncthreads();
    if (t < NFLAT) {
        float a = 0.f;
        #pragma unroll
        for (int w2 = 0; w2 < 16; ++w2) a += red[w2][t];
        sbuf[t] = a;
    }
    __syncthreads();
    if (t < 256) {   // squash(s0/16) -> osum  (16 threads per j, 2 d's each)
        const int j = t >> 4, g = t & 15;
        const int n0 = j * 32 + 2 * g;
        float v0 = sbuf[n0] * 0.0625f, v1 = sbuf[n0 + 1] * 0.0625f;
        float p = v0 * v0 + v1 * v1;
        p += __shfl_xor(p, 1); p += __shfl_xor(p, 2);
        p += __shfl_xor(p, 4); p += __shfl_xor(p, 8);
        float sc = (p / (1.f + p)) / sqrtf(p + 1e-7f);
        osum[n0] = sc * v0; osum[n0 + 1] = sc * v1;
    }
    __syncthreads();

    // ---- iters 1,2: d = dot(osum,u); softmax_j; acc += c*u ----
    for (int r = 1; r <= 2; ++r) {
        float os[8];
        #pragma unroll
        for (int e = 0; e < 8; ++e) { os[e] = osum[l * 8 + e]; acc[e] = 0.f; }
        #pragma unroll 2
        for (int ii = 0; ii < 32; ++ii) {
            union { uint4 v; u16 h[8]; } tmp;
            tmp.v = *(const uint4*)&ubase[(size_t)ii * NFLAT];
            float u[8];
            #pragma unroll
            for (int e = 0; e < 8; ++e) u[e] = b2f(tmp.h[e]);
            float d = 0.f;
            #pragma unroll
            for (int e = 0; e < 8; ++e) d += u[e] * os[e];
            d += __shfl_xor(d, 1); d += __shfl_xor(d, 2);   // quad = one j
            float mx = d;
            mx = fmaxf(mx, __shfl_xor(mx, 4));  mx = fmaxf(mx, __shfl_xor(mx, 8));
            mx = fmaxf(mx, __shfl_xor(mx, 16)); mx = fmaxf(mx, __shfl_xor(mx, 32));
            float ex = __expf(d - mx);
            float ss = ex;
            ss += __shfl_xor(ss, 4);  ss += __shfl_xor(ss, 8);
            ss += __shfl_xor(ss, 16); ss += __shfl_xor(ss, 32);
            float c = ex / ss;
            #pragma unroll
            for (int e = 0; e < 8; ++e) acc[e] += c * u[e];
        }
        #pragma unroll
        for (int e = 0; e < 8; ++e) red[wv][l * 8 + e] = acc[e];
        __syncthreads();
        if (t < NFLAT) {
            float a = 0.f;
            #pragma unroll
            for (int w2 = 0; w2 < 16; ++w2) a += red[w2][t];
            sbuf[t] = a;
        }
        __syncthreads();
        if (t < 256) {
            const int j = t >> 4, g = t & 15;
            const int n0 = j * 32 + 2 * g;
            float w0 = sbuf[n0], w1 = sbuf[n0 + 1];
            float p = w0 * w0 + w1 * w1;
            p += __shfl_xor(p, 1); p += __shfl_xor(p, 2);
            p += __shfl_xor(p, 4); p += __shfl_xor(p, 8);
            float sc = (p / (1.f + p)) / sqrtf(p + 1e-7f);
            if (r == 1) {
                // v1 = squash(s1); dot-vector for next iter is v0 + v1
                osum[n0]     += sc * w0;
                osum[n0 + 1] += sc * w1;
            } else {
                out[b * NFLAT + n0]     = sc * w0;
                out[b * NFLAT + n0 + 1] = sc * w1;
            }
        }
        __syncthreads();
    }
}

extern "C" void kernel_launch(void* const* d_in, const int* in_sizes, int n_in,
                              void* d_out, int out_size, void* d_ws, size_t ws_size,
                              hipStream_t stream) {
    // fp32 inputs (established R4). Resolve by element count.
    const float* x = nullptr;
    const float* W = nullptr;
    for (int a = 0; a < n_in; ++a) {
        if (in_sizes[a] == 64 * 512 * 128) x = (const float*)d_in[a];
        else if (in_sizes[a] == 512 * 16 * 128 * 32) W = (const float*)d_in[a];
    }
    if (!x) x = (const float*)d_in[0];
    if (!W) W = (const float*)d_in[1];

    u16* uhat = (u16*)d_ws;          // 2 * 64*512*512 bytes = 33.5 MB
    float* out = (float*)d_out;

    hipLaunchKernelGGL(gemm_kernel, dim3(2048), dim3(256), 0, stream, x, W, uhat);
    hipLaunchKernelGGL(route_all, dim3(64), dim3(1024), 0, stream, uhat, out);
}

// Round 3
// 240.525 us; speedup vs baseline: 4.2275x; 1.0542x over previous
//
#include <hip/hip_runtime.h>

typedef unsigned short u16;
typedef unsigned int u32;
typedef unsigned long long u64;
typedef __attribute__((ext_vector_type(8))) short short8;
typedef __attribute__((ext_vector_type(4))) float f32x4;

#define ICAPS 512
#define IDIM 128
#define NFLAT 512  // NCAPS(16) * ODIM(32)

__device__ __forceinline__ float b2f(u16 h) {
    union { u32 u; float f; } x; x.u = ((u32)h) << 16; return x.f;
}
__device__ __forceinline__ u16 f2b(float f) {
    union { float f; u32 u; } x; x.f = f;
    return (u16)((x.u + 0x7FFFu + ((x.u >> 16) & 1u)) >> 16);
}

// ---------------------------------------------------------------------------
// GEMM: u_hat[b,i,n] = sum_k x[b,i,k]*W[i,j(n),k,d(n)], n=j*32+d. fp32 inputs.
// EXACT round-0 proven version (245.9 µs config): W direct-to-register,
// read once grid-wide; scatter epilogue (32x2B per thread, 32B/16-lane seg).
// ---------------------------------------------------------------------------
__global__ __launch_bounds__(256, 4) void gemm_kernel(const float* __restrict__ x,
                                                      const float* __restrict__ W,
                                                      u16* __restrict__ uhat) {
    __shared__ __align__(16) u16 As[64 * 136];   // x[b][k] bf16, pitch 136
    const int i = blockIdx.x >> 2;
    const int chunk = blockIdx.x & 3;
    const int t = threadIdx.x;

    // Stage A: 64 rows x 128 k of x for this i; 2048 float4, 8/thread
    {
        const float4* xa = (const float4*)x;
        float4 av[8];
        #pragma unroll
        for (int l = 0; l < 8; ++l) {
            int id = l * 256 + t;
            av[l] = xa[(size_t)((id >> 5) * ICAPS + i) * 32 + (id & 31)];
        }
        #pragma unroll
        for (int l = 0; l < 8; ++l) {
            int id = l * 256 + t;
            int row = id >> 5, kq = id & 31;
            union { u16 h[4]; u64 q; } pk;
            pk.h[0] = f2b(av[l].x); pk.h[1] = f2b(av[l].y);
            pk.h[2] = f2b(av[l].z); pk.h[3] = f2b(av[l].w);
            *(u64*)&As[row * 136 + kq * 4] = pk.q;
        }
    }
    __syncthreads();

    const int lane = t & 63;
    const int w = t >> 6;
    const int ln = lane & 15;
    const int q = lane >> 4;

    const float* colbase[2];
    #pragma unroll
    for (int nt = 0; nt < 2; ++nt) {
        int c = (2 * w + nt) * 16 + ln;
        int jj = c >> 5, d = c & 31;
        colbase[nt] = W + (size_t)(i * 16 + chunk * 4 + jj) * 128 * 32 + d;
    }

    f32x4 acc[4][2] = {};
    #pragma unroll
    for (int ks = 0; ks < 4; ++ks) {
        const int ko = ks * 32 + q * 8;
        short8 a[4], bb[2];
        #pragma unroll
        for (int mt = 0; mt < 4; ++mt)
            a[mt] = *(const short8*)&As[(mt * 16 + ln) * 136 + ko];
        #pragma unroll
        for (int nt = 0; nt < 2; ++nt) {
            const float* p = colbase[nt] + (size_t)ko * 32;
            float wv[8];
            #pragma unroll
            for (int e = 0; e < 8; ++e) wv[e] = p[e * 32];   // offset e*128B imm
            #pragma unroll
            for (int e = 0; e < 8; ++e) bb[nt][e] = (short)f2b(wv[e]);
        }
        #pragma unroll
        for (int mt = 0; mt < 4; ++mt)
            #pragma unroll
            for (int nt = 0; nt < 2; ++nt)
                acc[mt][nt] = __builtin_amdgcn_mfma_f32_16x16x32_bf16(a[mt], bb[nt], acc[mt][nt], 0, 0, 0);
    }
    // C/D: col = lane&15, row = q*4 + reg (m89/m91-verified)
    #pragma unroll
    for (int mt = 0; mt < 4; ++mt)
        #pragma unroll
        for (int nt = 0; nt < 2; ++nt) {
            int n = chunk * 128 + (2 * w + nt) * 16 + ln;
            #pragma unroll
            for (int r = 0; r < 4; ++r) {
                int brow = mt * 16 + q * 4 + r;
                uhat[((size_t)brow * ICAPS + i) * NFLAT + n] = f2b(acc[mt][nt][r]);
            }
        }
}

// ---------------------------------------------------------------------------
// p0: q0[bx][n] = sum_{i in slice} uhat[b,i,n]; bx = b*16+ch. No atomics.
// ---------------------------------------------------------------------------
__global__ __launch_bounds__(256) void p0_kernel(const u16* __restrict__ uhat,
                                                 float* __restrict__ q0) {
    __shared__ __align__(16) float red[4][NFLAT];
    const int b = blockIdx.x >> 4;
    const int ch = blockIdx.x & 15;
    const int t = threadIdx.x;
    const int wv = t >> 6, l = t & 63;
    float acc[8] = {0.f, 0.f, 0.f, 0.f, 0.f, 0.f, 0.f, 0.f};
    for (int ii = 0; ii < 8; ++ii) {
        int i = ch * 32 + wv * 8 + ii;
        union { uint4 v; u16 h[8]; } tmp;
        tmp.v = *(const uint4*)&uhat[((size_t)b * ICAPS + i) * NFLAT + l * 8];
        #pragma unroll
        for (int e = 0; e < 8; ++e) acc[e] += b2f(tmp.h[e]);
    }
    #pragma unroll
    for (int e = 0; e < 8; ++e) red[wv][l * 8 + e] = acc[e];
    __syncthreads();
    q0[(size_t)blockIdx.x * NFLAT + t] =
        red[0][t] + red[1][t] + red[2][t] + red[3][t];
    q0[(size_t)blockIdx.x * NFLAT + 256 + t] =
        red[0][t + 256] + red[1][t + 256] + red[2][t + 256] + red[3][t + 256];
}

// combine: s[b][n] = sum_ch q[b*16+ch][n]
__global__ __launch_bounds__(256) void combine_kernel(const float* __restrict__ q,
                                                      float* __restrict__ s) {
    const int b = blockIdx.x, t = threadIdx.x;
    #pragma unroll
    for (int rep = 0; rep < 2; ++rep) {
        int n = rep * 256 + t;
        float acc = 0.f;
        #pragma unroll
        for (int ch = 0; ch < 16; ++ch)
            acc += q[(size_t)(b * 16 + ch) * NFLAT + n];
        s[b * NFLAT + n] = acc;
    }
}

__device__ __forceinline__ void squash_osum(const float* __restrict__ s0,
                                            const float* __restrict__ s1,
                                            float* __restrict__ osum,
                                            int b, int t, int use1) {
    const int j = t >> 4, g = t & 15;   // 16 threads per j, 2 d's each
    const int n0 = j * 32 + 2 * g;
    float v0 = s0[b * NFLAT + n0] * 0.0625f;
    float v1 = s0[b * NFLAT + n0 + 1] * 0.0625f;
    float p = v0 * v0 + v1 * v1;
    p += __shfl_xor(p, 1); p += __shfl_xor(p, 2);
    p += __shfl_xor(p, 4); p += __shfl_xor(p, 8);
    float sc = (p / (1.f + p)) / sqrtf(p + 1e-7f);
    float o0 = sc * v0, o1 = sc * v1;
    if (use1) {
        float w0 = s1[b * NFLAT + n0];
        float w1 = s1[b * NFLAT + n0 + 1];
        float pq = w0 * w0 + w1 * w1;
        pq += __shfl_xor(pq, 1); pq += __shfl_xor(pq, 2);
        pq += __shfl_xor(pq, 4); pq += __shfl_xor(pq, 8);
        float sc1 = (pq / (1.f + pq)) / sqrtf(pq + 1e-7f);
        o0 += sc1 * w0; o1 += sc1 * w1;
    }
    osum[n0] = o0; osum[n0 + 1] = o1;
}

// route: osum = squash(s0/16) (+ squash(s1) if use1); per (b,i) in slice:
// d_j = dot(osum, uhat); c = softmax_j; qout[bx] += c*uhat. No atomics.
// NEW vs R0: softmax WITHOUT max-subtraction. |d| <= |osum||u_row| ~ 14,
// exp() safe in fp32 by a huge margin -> saves 4 shuffles + 4 fmax per i.
// Division via __fdividef (rcp+mul; rel err ~1e-6 << 2^-8 tolerance).
// ---------------------------------------------------------------------------
__global__ __launch_bounds__(256) void route_kernel(const u16* __restrict__ uhat,
                                                    const float* __restrict__ s0,
                                                    const float* __restrict__ s1,
                                                    float* __restrict__ qout,
                                                    int use1) {
    __shared__ float osum[NFLAT];
    __shared__ __align__(16) float red[4][NFLAT];
    const int b = blockIdx.x >> 4;
    const int ch = blockIdx.x & 15;
    const int t = threadIdx.x;
    squash_osum(s0, s1, osum, b, t, use1);
    __syncthreads();
    const int wv = t >> 6, l = t & 63;
    float os[8], acc[8];
    #pragma unroll
    for (int e = 0; e < 8; ++e) { os[e] = osum[l * 8 + e]; acc[e] = 0.f; }
    for (int ii = 0; ii < 8; ++ii) {
        int i = ch * 32 + wv * 8 + ii;
        union { uint4 v; u16 h[8]; } tmp;
        tmp.v = *(const uint4*)&uhat[((size_t)b * ICAPS + i) * NFLAT + l * 8];
        float u[8];
        #pragma unroll
        for (int e = 0; e < 8; ++e) u[e] = b2f(tmp.h[e]);
        float d = 0.f;
        #pragma unroll
        for (int e = 0; e < 8; ++e) d += u[e] * os[e];
        d += __shfl_xor(d, 1); d += __shfl_xor(d, 2);   // quad = one j
        float ex = __expf(d);                            // no max-sub: |d|<~20
        float ss = ex;
        ss += __shfl_xor(ss, 4);  ss += __shfl_xor(ss, 8);
        ss += __shfl_xor(ss, 16); ss += __shfl_xor(ss, 32);
        float c = __fdividef(ex, ss);
        #pragma unroll
        for (int e = 0; e < 8; ++e) acc[e] += c * u[e];
    }
    #pragma unroll
    for (int e = 0; e < 8; ++e) red[wv][l * 8 + e] = acc[e];
    __syncthreads();
    qout[(size_t)blockIdx.x * NFLAT + t] =
        red[0][t] + red[1][t] + red[2][t] + red[3][t];
    qout[(size_t)blockIdx.x * NFLAT + 256 + t] =
        red[0][t + 256] + red[1][t + 256] + red[2][t + 256] + red[3][t + 256];
}

// fin: s2[b][n] = sum_ch q2; out = squash(s2), fp32
__global__ __launch_bounds__(256) void fin_kernel(const float* __restrict__ q2,
                                                  float* __restrict__ out) {
    const int b = blockIdx.x, t = threadIdx.x;
    const int j = t >> 4, g = t & 15;
    const int n0 = j * 32 + 2 * g;
    float v0 = 0.f, v1 = 0.f;
    #pragma unroll
    for (int ch = 0; ch < 16; ++ch) {
        v0 += q2[(size_t)(b * 16 + ch) * NFLAT + n0];
        v1 += q2[(size_t)(b * 16 + ch) * NFLAT + n0 + 1];
    }
    float p = v0 * v0 + v1 * v1;
    p += __shfl_xor(p, 1); p += __shfl_xor(p, 2);
    p += __shfl_xor(p, 4); p += __shfl_xor(p, 8);
    float sc = (p / (1.f + p)) / sqrtf(p + 1e-7f);
    out[b * NFLAT + n0]     = sc * v0;
    out[b * NFLAT + n0 + 1] = sc * v1;
}

extern "C" void kernel_launch(void* const* d_in, const int* in_sizes, int n_in,
                              void* d_out, int out_size, void* d_ws, size_t ws_size,
                              hipStream_t stream) {
    // fp32 inputs (established R4). Resolve by element count.
    const float* x = nullptr;
    const float* W = nullptr;
    for (int a = 0; a < n_in; ++a) {
        if (in_sizes[a] == 64 * 512 * 128) x = (const float*)d_in[a];
        else if (in_sizes[a] == 512 * 16 * 128 * 32) W = (const float*)d_in[a];
    }
    if (!x) x = (const float*)d_in[0];
    if (!W) W = (const float*)d_in[1];

    char* ws = (char*)d_ws;
    const size_t U = 2ull * 64 * 512 * 512;          // uhat bytes = 33.5 MB
    u16*   uhat = (u16*)ws;
    float* q0 = (float*)(ws + U);                    // 1024*512 f32 = 2 MB
    float* q1 = (float*)(ws + U + (2ull << 20));
    float* q2 = (float*)(ws + U + (4ull << 20));
    float* s0 = (float*)(ws + U + (6ull << 20));     // 64*512 f32 = 128 KB
    float* s1 = (float*)(ws + U + (6ull << 20) + (128ull << 10));
    float* out = (float*)d_out;

    hipLaunchKernelGGL(gemm_kernel, dim3(2048), dim3(256), 0, stream, x, W, uhat);
    hipLaunchKernelGGL(p0_kernel, dim3(1024), dim3(256), 0, stream, uhat, q0);
    hipLaunchKernelGGL(combine_kernel, dim3(64), dim3(256), 0, stream, q0, s0);
    hipLaunchKernelGGL(route_kernel, dim3(1024), dim3(256), 0, stream, uhat, s0, s0, q1, 0);
    hipLaunchKernelGGL(combine_kernel, dim3(64), dim3(256), 0, stream, q1, s1);
    hipLaunchKernelGGL(route_kernel, dim3(1024), dim3(256), 0, stream, uhat, s0, s1, q2, 1);
    hipLaunchKernelGGL(fin_kernel, dim3(64), dim3(256), 0, stream, q2, out);
}